// Round 7
// baseline (270.869 us; speedup 1.0000x reference)
//
#include <hip/hip_runtime.h>
#include <hip/hip_bf16.h>

// ---------------------------------------------------------------------------
// MHA fused pipeline, bf16 MFMA path.
//   pre_kernel: {x, W_in, W_out} f32 -> bf16 + mask -> key-bias (one launch)
//   qkv = x @ W_in^T + b_in   (128x128-tile gemm_nt, 32x32x16 MFMA)
//   flash attention: 8-warp 32x32 swapped-QK^T, in-register softmax,
//     XCD-chunked block swizzle (panels L2-resident per XCD)
//   out = ctx @ W_out^T + b_out  (gemm_nt, f32 output)
// B=2 S=2048 E=2048 H=16 D=128 hard-coded where convenient.
// R3-R5 lesson: pipelined 2/8-phase GEMM ports all landed 775-800 TF vs
// gemm_nt's 897 (2+ blocks/CU inter-block overlap wins) — keep gemm_nt
// structure; this round only swaps MFMA shape 16x16x32 -> 32x32x16
// (µbench ceiling 2176 -> 2495 TF, mapping proven in attn_kernel).
// ---------------------------------------------------------------------------

typedef __bf16 bf16;
typedef __bf16 bf16x8 __attribute__((ext_vector_type(8)));
typedef __bf16 bf16x4 __attribute__((ext_vector_type(4)));
typedef float  f32x4  __attribute__((ext_vector_type(4)));
typedef float  f32x16 __attribute__((ext_vector_type(16)));

#define LOG2E 1.4426950408889634074f
#define SM_SCALE 0.08838834764831843f /* 1/sqrt(128) */

#if defined(__has_builtin)
#if __has_builtin(__builtin_amdgcn_exp2f)
#define EXP2(x) __builtin_amdgcn_exp2f(x)
#else
#define EXP2(x) exp2f(x)
#endif
#else
#define EXP2(x) exp2f(x)
#endif

// global -> LDS direct copy, 16B per lane. LDS dest is wave-uniform base +
// lane*16 (hardware rule, m104); global src is per-lane.
#define GLOAD_LDS16(gp, lp)                                                    \
  __builtin_amdgcn_global_load_lds(                                           \
      (__attribute__((address_space(1))) void*)(gp),                          \
      (__attribute__((address_space(3))) void*)(lp), 16, 0, 0)

__device__ inline unsigned int cvtpk_bf16(float lo, float hi) {
  unsigned int r;
  asm("v_cvt_pk_bf16_f32 %0, %1, %2" : "=v"(r) : "v"(lo), "v"(hi));
  return r;
}
// v_permlane32_swap_b32: a.hi_lanes <-> b.lo_lanes
__device__ inline void plane32_swap(unsigned int& a, unsigned int& b) {
  asm volatile("v_permlane32_swap_b32 %0, %1" : "+v"(a), "+v"(b));
}

// ---------------------------------------------------------------------------
// Kernel 1: fused pre-pass. Blocks [0,12288): f32->bf16 convert (8 elem/thr);
// block 12288: mask -> additive key bias with storage-dtype sniffing.
// Ranges: [0,4096)->x, [4096,10240)->W_in, [10240,12288)->W_out. Exact fit.
__global__ void pre_kernel(const float* __restrict__ x,
                           const float* __restrict__ W_in,
                           const float* __restrict__ W_out,
                           const unsigned char* __restrict__ mraw,
                           bf16* __restrict__ xb, bf16* __restrict__ wib,
                           bf16* __restrict__ wob,
                           float* __restrict__ kbias) {
  const int bid = blockIdx.x;
  if (bid < 12288) {
    const float* in;
    bf16* out;
    int i;
    if (bid < 4096) {
      in = x; out = xb; i = bid * 256 + threadIdx.x;
    } else if (bid < 10240) {
      in = W_in; out = wib; i = (bid - 4096) * 256 + threadIdx.x;
    } else {
      in = W_out; out = wob; i = (bid - 10240) * 256 + threadIdx.x;
    }
    const float4* p = (const float4*)in + (size_t)i * 2;
    float4 a = p[0], c = p[1];
    bf16x8 v;
    v[0] = (bf16)a.x; v[1] = (bf16)a.y; v[2] = (bf16)a.z; v[3] = (bf16)a.w;
    v[4] = (bf16)c.x; v[5] = (bf16)c.y; v[6] = (bf16)c.z; v[7] = (bf16)c.w;
    *((bf16x8*)out + i) = v;
    return;
  }
  // ---- mask -> bias (block 12288) ----
  // dtype sniff from first 4096 bytes: nonzero @ (i%4==1) -> 1-byte bool;
  // else @ (i%4 in 2,3) -> f32; else @ (i%8==4) -> i32; else i64.
  __shared__ int f1, f23, f84;
  if (threadIdx.x == 0) { f1 = 0; f23 = 0; f84 = 0; }
  __syncthreads();
  int a1 = 0, a23 = 0, a84 = 0;
  for (int i = threadIdx.x; i < 4096; i += blockDim.x) {
    unsigned char v = mraw[i];
    if (v) {
      int m4 = i & 3;
      if (m4 == 1) a1 = 1;
      else if (m4 >= 2) a23 = 1;
      else if ((i & 7) == 4) a84 = 1;
    }
  }
  if (a1) f1 = 1;
  if (a23) f23 = 1;
  if (a84) f84 = 1;
  __syncthreads();
  const bool isByte = (f1 != 0);
  const bool isF32 = !isByte && (f23 != 0);
  const bool isI32 = !isByte && !isF32 && (f84 != 0);
  for (int i = threadIdx.x; i < 4096; i += blockDim.x) {
    int m;
    if (isByte)      m = (mraw[i] != 0);
    else if (isF32)  m = (((const float*)mraw)[i] != 0.0f);
    else if (isI32)  m = (((const int*)mraw)[i] != 0);
    else             m = (((const long long*)mraw)[i] != 0LL);
    kbias[i] = m ? -30000.0f : 0.0f;  // exp2-domain "-inf"
  }
}

// ---------------------------------------------------------------------------
// Kernel 2: NT GEMM  C[M,N] = A[M,K] * B[N,K]^T + bias[N]
// m97 structure (128x128 tile, BK=64, 4 waves 2x2, global_load_lds w16,
// XOR swizzle on source+ds_read) with 32x32x16 MFMA inner math:
// per wave 64x64 out = 2x2 f32x16 accs; per K-tile 16 mfma + 16 ds_read_b128.
// A-frag: lane row = base+l31, k = hb*8+j (attn-proven mapping).
// C layout: col = l31, row = (r&3)+8*(r>>2)+4*hb (m74/m101-verified).
// EPI=0: f32 store. EPI=1: qkv routing (cols<4096 -> qkv; else vt transposed).
template <int EPI>
__global__ __launch_bounds__(256, 2) void gemm_nt(
    const bf16* __restrict__ A, const bf16* __restrict__ B,
    const float* __restrict__ bias, void* __restrict__ Cout,
    bf16* __restrict__ vt, int M, int N, int K) {
  const int lane = threadIdx.x & 63;
  const int w = threadIdx.x >> 6;
  const int wr = w >> 1, wc = w & 1;
  const int l31 = lane & 31, hb = lane >> 5;

  const int nwg = gridDim.x;  // multiple of 8 for all launches
  const int cpx = nwg >> 3;
  const int bid = blockIdx.x;
  const int swz = (bid & 7) * cpx + (bid >> 3);
  const int mtiles = M >> 7;
  const int mt = swz % mtiles, nt = swz / mtiles;
  const int m0 = mt << 7, n0 = nt << 7;

  __shared__ __align__(16) unsigned char smem[32768];
  unsigned char* sA = smem;
  unsigned char* sB = smem + 16384;

  const f32x16 Z16 = {0.f, 0.f, 0.f, 0.f, 0.f, 0.f, 0.f, 0.f,
                      0.f, 0.f, 0.f, 0.f, 0.f, 0.f, 0.f, 0.f};
  f32x16 acc[2][2];
#pragma unroll
  for (int i = 0; i < 2; i++)
#pragma unroll
    for (int j = 0; j < 2; j++) acc[i][j] = Z16;

  const int chunkbase = w * 1024 + lane * 16;

  for (int kt = 0; kt < K; kt += 64) {
#pragma unroll
    for (int c = 0; c < 4; c++) {
      int p = c * 4096 + chunkbase;
      int row = p >> 7, off = p & 127;
      int sb = off ^ ((row & 7) << 4);
      GLOAD_LDS16(A + (size_t)(m0 + row) * K + kt + (sb >> 1),
                  sA + c * 4096 + w * 1024);
      GLOAD_LDS16(B + (size_t)(n0 + row) * K + kt + (sb >> 1),
                  sB + c * 4096 + w * 1024);
    }
    __syncthreads();
#pragma unroll
    for (int ks = 0; ks < 4; ks++) {  // K-steps of 16
      bf16x8 af[2], bfr[2];
#pragma unroll
      for (int i = 0; i < 2; i++) {
        int ar = wr * 64 + i * 32 + l31;
        af[i] = *(const bf16x8*)(sA + ar * 128 +
                                 ((ks * 32 + hb * 16) ^ ((ar & 7) << 4)));
        int br = wc * 64 + i * 32 + l31;
        bfr[i] = *(const bf16x8*)(sB + br * 128 +
                                  ((ks * 32 + hb * 16) ^ ((br & 7) << 4)));
      }
#pragma unroll
      for (int i = 0; i < 2; i++)
#pragma unroll
        for (int j = 0; j < 2; j++)
          acc[i][j] = __builtin_amdgcn_mfma_f32_32x32x16_bf16(
              af[i], bfr[j], acc[i][j], 0, 0, 0);
    }
    __syncthreads();
  }

  // epilogue: 32x32 C frag layout col=l31, row=(r&3)+8*(r>>2)+4*hb
#pragma unroll
  for (int mi = 0; mi < 2; mi++) {
#pragma unroll
    for (int nj = 0; nj < 2; nj++) {
      const int row0 = m0 + wr * 64 + mi * 32;
      const int col = n0 + wc * 64 + nj * 32 + l31;
      const float bv = bias[col];
      f32x16 v = acc[mi][nj];
#pragma unroll
      for (int r = 0; r < 16; r++) v[r] += bv;
      if (EPI == 0) {
        float* Cf = (float*)Cout;
#pragma unroll
        for (int r = 0; r < 16; r++) {
          int row = row0 + (r & 3) + 8 * (r >> 2) + 4 * hb;
          Cf[(size_t)row * N + col] = v[r];
        }
      } else {
        bf16* Cb = (bf16*)Cout;
        if (col < 4096) {  // q or k section (uniform per block)
#pragma unroll
          for (int r = 0; r < 16; r++) {
            int row = row0 + (r & 3) + 8 * (r >> 2) + 4 * hb;
            Cb[(size_t)row * 6144 + col] = (bf16)v[r];
          }
        } else {  // v section -> transposed vt[B,H,D,S], bf16x4 along s
          int dg = col - 4096;
          int hh = dg >> 7, dd = dg & 127;
#pragma unroll
          for (int q = 0; q < 4; q++) {
            int rowq = row0 + q * 8 + 4 * hb;  // rows rowq .. rowq+3
            int bb = rowq >> 11, ss = rowq & 2047;
            bf16x4 pk;
#pragma unroll
            for (int j2 = 0; j2 < 4; j2++) pk[j2] = (bf16)v[q * 4 + j2];
            *(bf16x4*)(vt + (size_t)((bb * 16 + hh) * 128 + dd) * 2048 + ss) =
                pk;
          }
        }
      }
    }
  }
}

// ---------------------------------------------------------------------------
// Kernel 3: flash attention, 8-warp 32x32 swapped-QK^T (proven R2 structure)
// + XCD-chunked block swizzle: flat grid 256; swz=(f&7)*32+(f>>3) gives each
// XCD 4 whole (b,h) panels (4MB K+VT, L2-resident) instead of 32 partial.
__global__ __launch_bounds__(512, 2) void attn_kernel(
    const bf16* __restrict__ qkv, const bf16* __restrict__ vt,
    const float* __restrict__ kbias, bf16* __restrict__ ctx) {
  const int tid = threadIdx.x;
  const int lane = tid & 63;
  const int w = tid >> 6;
  const int l31 = lane & 31;
  const int hb = lane >> 5;

  // XCD-chunked decode (256 blocks): qt fastest within a panel chunk.
  const int f = blockIdx.x;
  const int swzb = (f & 7) * 32 + (f >> 3);
  const int qt = swzb & 7;
  const int h = (swzb >> 3) & 15;
  const int b = swzb >> 7;

  __shared__ __align__(16) unsigned char smem[65536];  // 2 x (16K K + 16K VT)

  const int qrow0 = qt * 256 + w * 32;
  const size_t tokbase = (size_t)b * 2048;
  const size_t vtbase = (size_t)((b * 16 + h) * 128) * 2048;
  const float* biasb = kbias + b * 2048;
  const float Cmul = SM_SCALE * LOG2E;

  auto stage = [&](int t, int bufsel) {
    const int kv0 = t * 64;
    unsigned char* base = smem + bufsel * 32768;
#pragma unroll
    for (int c = 0; c < 2; c++) {
      int p = c * 8192 + tid * 16;
      int rowk = p >> 8, offk = p & 255;  // K: 64 rows x 256B
      int sbk = offk ^ ((rowk & 15) << 4);
      GLOAD_LDS16(qkv + (tokbase + kv0 + rowk) * 6144 + 2048 + h * 128 +
                      (sbk >> 1),
                  base + c * 8192 + w * 1024);
      int rowv = p >> 7, offv = p & 127;  // VT: 128 rows x 128B
      int sbv = offv ^ ((rowv & 7) << 4);
      GLOAD_LDS16(vt + vtbase + (size_t)rowv * 2048 + kv0 + (sbv >> 1),
                  base + 16384 + c * 8192 + w * 1024);
    }
  };

  stage(0, 0);

  // Q B-frags from global (lane: q=l31, d = ds*16 + hb*8 + j)
  bf16x8 qf[8];
#pragma unroll
  for (int ds = 0; ds < 8; ds++)
    qf[ds] = *(const bf16x8*)(qkv + (tokbase + qrow0 + l31) * 6144 + h * 128 +
                              ds * 16 + hb * 8);

  const f32x16 Z16 = {0.f, 0.f, 0.f, 0.f, 0.f, 0.f, 0.f, 0.f,
                      0.f, 0.f, 0.f, 0.f, 0.f, 0.f, 0.f, 0.f};
  f32x16 opv[4];  // O: row q=(r&3)+8*(r>>2)+4hb, col d=d0*32+l31
#pragma unroll
  for (int d0 = 0; d0 < 4; d0++) opv[d0] = Z16;
  float mrun = -15000.0f, lrun = 0.0f;

  __syncthreads();

  for (int t = 0; t < 32; t++) {
    const int buf = t & 1;
    const int kv0 = t * 64;
    if (t < 31) stage(t + 1, buf ^ 1);
    unsigned char* sK = smem + buf * 32768;
    unsigned char* sVT = sK + 16384;

    f32x4 bb[2][2][2];
#pragma unroll
    for (int kb = 0; kb < 2; kb++)
#pragma unroll
      for (int sb = 0; sb < 2; sb++)
#pragma unroll
        for (int g = 0; g < 2; g++)
          bb[kb][sb][g] = *(const f32x4*)(biasb + kv0 + kb * 32 + sb * 16 +
                                          g * 8 + 4 * hb);

    // ---- S^T = K Q^T : acc col = q = l31, row = key ----
    f32x16 accs[2];
    accs[0] = Z16; accs[1] = Z16;
    __builtin_amdgcn_s_setprio(1);
#pragma unroll
    for (int ds = 0; ds < 8; ds++) {
#pragma unroll
      for (int kb = 0; kb < 2; kb++) {
        int row = kb * 32 + l31;
        bf16x8 kf = *(const bf16x8*)(
            sK + row * 256 + ((ds * 32 + hb * 16) ^ ((row & 15) << 4)));
        accs[kb] = __builtin_amdgcn_mfma_f32_32x32x16_bf16(kf, qf[ds],
                                                           accs[kb], 0, 0, 0);
      }
    }
    __builtin_amdgcn_s_setprio(0);

    // ---- softmax in-register (lane owns q=l31, keys of its hb half) ----
#pragma unroll
    for (int kb = 0; kb < 2; kb++)
#pragma unroll
      for (int r = 0; r < 16; r++)
        accs[kb][r] =
            accs[kb][r] * Cmul + bb[kb][r >> 3][(r >> 2) & 1][r & 3];

    float vmax = accs[0][0];
#pragma unroll
    for (int kb = 0; kb < 2; kb++)
#pragma unroll
      for (int r = 0; r < 16; r++) vmax = fmaxf(vmax, accs[kb][r]);
    vmax = fmaxf(vmax, __shfl_xor(vmax, 32));

    if (__any(vmax > mrun + 8.0f)) {  // defer-max (T13)
      float mnew = fmaxf(mrun, vmax);
      float corr = EXP2(mrun - mnew);
      mrun = mnew;
      lrun *= corr;
#pragma unroll
      for (int r = 0; r < 16; r++) {
        float cv = __shfl(corr, (r & 3) + 8 * (r >> 2) + 4 * hb);
#pragma unroll
        for (int d0 = 0; d0 < 4; d0++) opv[d0][r] *= cv;
      }
    }

    float vsum = 0.0f;
#pragma unroll
    for (int kb = 0; kb < 2; kb++)
#pragma unroll
      for (int r = 0; r < 16; r++) {
        float p = EXP2(accs[kb][r] - mrun);
        accs[kb][r] = p;
        vsum += p;
      }
    vsum += __shfl_xor(vsum, 32);
    lrun += vsum;

    // ---- P -> bf16 A-frags via cvt_pk + permlane32_swap (T12) ----
    union { unsigned int w4[4]; bf16x8 v; } paf[4];
#pragma unroll
    for (int kb = 0; kb < 2; kb++)
#pragma unroll
      for (int sb = 0; sb < 2; sb++) {
        int r0 = sb * 8;
        unsigned int a0 = cvtpk_bf16(accs[kb][r0 + 0], accs[kb][r0 + 1]);
        unsigned int a1 = cvtpk_bf16(accs[kb][r0 + 2], accs[kb][r0 + 3]);
        unsigned int c0 = cvtpk_bf16(accs[kb][r0 + 4], accs[kb][r0 + 5]);
        unsigned int c1 = cvtpk_bf16(accs[kb][r0 + 6], accs[kb][r0 + 7]);
        plane32_swap(a0, c0);
        plane32_swap(a1, c1);
        int ks = kb * 2 + sb;
        paf[ks].w4[0] = a0; paf[ks].w4[1] = a1;
        paf[ks].w4[2] = c0; paf[ks].w4[3] = c1;
      }

    // ---- O += P V  (B-frag from VT: lane d=d0*32+l31, k=ks*16+hb*8+j) ----
    __builtin_amdgcn_s_setprio(1);
#pragma unroll
    for (int ks = 0; ks < 4; ks++) {
#pragma unroll
      for (int d0 = 0; d0 < 4; d0++) {
        int row = d0 * 32 + l31;
        bf16x8 vf = *(const bf16x8*)(
            sVT + row * 128 + ((ks * 32 + hb * 16) ^ ((row & 7) << 4)));
        opv[d0] = __builtin_amdgcn_mfma_f32_32x32x16_bf16(paf[ks].v, vf,
                                                          opv[d0], 0, 0, 0);
      }
    }
    __builtin_amdgcn_s_setprio(0);

    __syncthreads();  // drains stage(t+1) vmcnt + protects dbuf swap
  }

  // ---- epilogue: ctx = O / l ----
  float linv = 1.0f / lrun;
#pragma unroll
  for (int r = 0; r < 16; r++) {
    float lv = __shfl(linv, (r & 3) + 8 * (r >> 2) + 4 * hb);
    int row = qrow0 + (r & 3) + 8 * (r >> 2) + 4 * hb;
#pragma unroll
    for (int d0 = 0; d0 < 4; d0++)
      ctx[(tokbase + row) * 2048 + h * 128 + d0 * 32 + l31] =
          (bf16)(opv[d0][r] * lv);
  }
}

// ---------------------------------------------------------------------------
extern "C" void kernel_launch(void* const* d_in, const int* in_sizes, int n_in,
                              void* d_out, int out_size, void* d_ws,
                              size_t ws_size, hipStream_t stream) {
  const float* x     = (const float*)d_in[0];
  const float* W_in  = (const float*)d_in[1];
  const float* b_in  = (const float*)d_in[2];
  const float* W_out = (const float*)d_in[3];
  const float* b_out = (const float*)d_in[4];
  const unsigned char* mask = (const unsigned char*)d_in[5];
  (void)in_sizes; (void)n_in; (void)out_size; (void)ws_size;

  char* ws = (char*)d_ws;
  bf16* xb    = (bf16*)(ws + 0);           //  16.78 MB  x bf16 [4096,2048]
  bf16* wib   = (bf16*)(ws + 16777216);    //  25.17 MB  W_in bf16 [6144,2048]
  bf16* wob   = (bf16*)(ws + 41943040);    //   8.39 MB  W_out bf16 [2048,2048]
  bf16* qkv   = (bf16*)(ws + 50331648);    //  50.33 MB  qkv bf16 [4096,6144]
  bf16* vt    = (bf16*)(ws + 100663296);   //  16.78 MB  V^T bf16 [B,H,D,S]
  bf16* ctx   = (bf16*)(ws + 117440512);   //  16.78 MB  ctx bf16 [4096,2048]
  float* kbias = (float*)(ws + 134217728); //  16 KB     key bias f32 [B*S]

  pre_kernel<<<12289, 256, 0, stream>>>(x, W_in, W_out, mask, xb, wib, wob,
                                        kbias);
  gemm_nt<1><<<1536, 256, 0, stream>>>(xb, wib, b_in, (void*)qkv, vt, 4096,
                                       6144, 2048);
  attn_kernel<<<256, 512, 0, stream>>>(qkv, vt, kbias, ctx);
  gemm_nt<0><<<512, 256, 0, stream>>>(ctx, wob, b_out, d_out, (bf16*)nullptr,
                                      4096, 2048, 2048);
}

// Round 8
// 268.925 us; speedup vs baseline: 1.0072x; 1.0072x over previous
//
#include <hip/hip_runtime.h>
#include <hip/hip_bf16.h>

// ---------------------------------------------------------------------------
// MHA fused pipeline, bf16 MFMA path.
//   pre_kernel: {x, W_in, W_out} f32 -> bf16 + mask -> key-bias (one launch)
//   qkv = x @ W_in^T + b_in   (128x128-tile gemm_nt, 32x32x16 MFMA,
//                              paired-row 256B LDS layout: conflict-free)
//   flash attention: 8-warp 32x32 swapped-QK^T, in-register softmax,
//     XCD-chunked block swizzle (panels L2-resident per XCD)
//   out = ctx @ W_out^T + b_out  (gemm_nt, f32 output)
// B=2 S=2048 E=2048 H=16 D=128 hard-coded where convenient.
// R7 lesson: 32x32 frag reads (32 rows @ same 16B col) on 128B-row LDS are a
// 4-way bank conflict (1.26e7 measured). Fix = attention's geometry: pair two
// tile rows into one 256B LDS row, swizzle (ldsrow&15)<<4 -> 16 slots, 2-way.
// ---------------------------------------------------------------------------

typedef __bf16 bf16;
typedef __bf16 bf16x8 __attribute__((ext_vector_type(8)));
typedef __bf16 bf16x4 __attribute__((ext_vector_type(4)));
typedef float  f32x4  __attribute__((ext_vector_type(4)));
typedef float  f32x16 __attribute__((ext_vector_type(16)));

#define LOG2E 1.4426950408889634074f
#define SM_SCALE 0.08838834764831843f /* 1/sqrt(128) */

#if defined(__has_builtin)
#if __has_builtin(__builtin_amdgcn_exp2f)
#define EXP2(x) __builtin_amdgcn_exp2f(x)
#else
#define EXP2(x) exp2f(x)
#endif
#else
#define EXP2(x) exp2f(x)
#endif

// global -> LDS direct copy, 16B per lane. LDS dest is wave-uniform base +
// lane*16 (hardware rule, m104); global src is per-lane.
#define GLOAD_LDS16(gp, lp)                                                    \
  __builtin_amdgcn_global_load_lds(                                           \
      (__attribute__((address_space(1))) void*)(gp),                          \
      (__attribute__((address_space(3))) void*)(lp), 16, 0, 0)

__device__ inline unsigned int cvtpk_bf16(float lo, float hi) {
  unsigned int r;
  asm("v_cvt_pk_bf16_f32 %0, %1, %2" : "=v"(r) : "v"(lo), "v"(hi));
  return r;
}
// v_permlane32_swap_b32: a.hi_lanes <-> b.lo_lanes
__device__ inline void plane32_swap(unsigned int& a, unsigned int& b) {
  asm volatile("v_permlane32_swap_b32 %0, %1" : "+v"(a), "+v"(b));
}

// ---------------------------------------------------------------------------
// Kernel 1: fused pre-pass. Blocks [0,12288): f32->bf16 convert (8 elem/thr);
// block 12288: mask -> additive key bias with storage-dtype sniffing.
// Ranges: [0,4096)->x, [4096,10240)->W_in, [10240,12288)->W_out. Exact fit.
__global__ void pre_kernel(const float* __restrict__ x,
                           const float* __restrict__ W_in,
                           const float* __restrict__ W_out,
                           const unsigned char* __restrict__ mraw,
                           bf16* __restrict__ xb, bf16* __restrict__ wib,
                           bf16* __restrict__ wob,
                           float* __restrict__ kbias) {
  const int bid = blockIdx.x;
  if (bid < 12288) {
    const float* in;
    bf16* out;
    int i;
    if (bid < 4096) {
      in = x; out = xb; i = bid * 256 + threadIdx.x;
    } else if (bid < 10240) {
      in = W_in; out = wib; i = (bid - 4096) * 256 + threadIdx.x;
    } else {
      in = W_out; out = wob; i = (bid - 10240) * 256 + threadIdx.x;
    }
    const float4* p = (const float4*)in + (size_t)i * 2;
    float4 a = p[0], c = p[1];
    bf16x8 v;
    v[0] = (bf16)a.x; v[1] = (bf16)a.y; v[2] = (bf16)a.z; v[3] = (bf16)a.w;
    v[4] = (bf16)c.x; v[5] = (bf16)c.y; v[6] = (bf16)c.z; v[7] = (bf16)c.w;
    *((bf16x8*)out + i) = v;
    return;
  }
  // ---- mask -> bias (block 12288) ----
  // dtype sniff from first 4096 bytes: nonzero @ (i%4==1) -> 1-byte bool;
  // else @ (i%4 in 2,3) -> f32; else @ (i%8==4) -> i32; else i64.
  __shared__ int f1, f23, f84;
  if (threadIdx.x == 0) { f1 = 0; f23 = 0; f84 = 0; }
  __syncthreads();
  int a1 = 0, a23 = 0, a84 = 0;
  for (int i = threadIdx.x; i < 4096; i += blockDim.x) {
    unsigned char v = mraw[i];
    if (v) {
      int m4 = i & 3;
      if (m4 == 1) a1 = 1;
      else if (m4 >= 2) a23 = 1;
      else if ((i & 7) == 4) a84 = 1;
    }
  }
  if (a1) f1 = 1;
  if (a23) f23 = 1;
  if (a84) f84 = 1;
  __syncthreads();
  const bool isByte = (f1 != 0);
  const bool isF32 = !isByte && (f23 != 0);
  const bool isI32 = !isByte && !isF32 && (f84 != 0);
  for (int i = threadIdx.x; i < 4096; i += blockDim.x) {
    int m;
    if (isByte)      m = (mraw[i] != 0);
    else if (isF32)  m = (((const float*)mraw)[i] != 0.0f);
    else if (isI32)  m = (((const int*)mraw)[i] != 0);
    else             m = (((const long long*)mraw)[i] != 0LL);
    kbias[i] = m ? -30000.0f : 0.0f;  // exp2-domain "-inf"
  }
}

// ---------------------------------------------------------------------------
// Kernel 2: NT GEMM  C[M,N] = A[M,K] * B[N,K]^T + bias[N]
// m97 structure (128x128 tile, BK=64, 4 waves 2x2, global_load_lds w16)
// with 32x32x16 MFMA and PAIRED-ROW LDS: tile elem (r,c) at byte
//   (r>>1)*256 + ((((r&1)<<7) | (c*2)) ^ (((r>>1)&15)<<4))
// -> frag reads (32 rows, fixed 16B col) hit 16 slots 2-way = conflict-free
// (attention-proven pattern). Staging pre-applies the inverse on the global
// source so global_load_lds can write linearly (rule #21).
// C layout: col = l31, row = (r&3)+8*(r>>2)+4*hb (m74/m101 + R7-verified).
// EPI=0: f32 store. EPI=1: qkv routing (cols<4096 -> qkv; else vt transposed).
template <int EPI>
__global__ __launch_bounds__(256, 2) void gemm_nt(
    const bf16* __restrict__ A, const bf16* __restrict__ B,
    const float* __restrict__ bias, void* __restrict__ Cout,
    bf16* __restrict__ vt, int M, int N, int K) {
  const int lane = threadIdx.x & 63;
  const int w = threadIdx.x >> 6;
  const int wr = w >> 1, wc = w & 1;
  const int l31 = lane & 31, hb = lane >> 5;

  const int nwg = gridDim.x;  // multiple of 8 for all launches
  const int cpx = nwg >> 3;
  const int bid = blockIdx.x;
  const int swz = (bid & 7) * cpx + (bid >> 3);
  const int mtiles = M >> 7;
  const int mt = swz % mtiles, nt = swz / mtiles;
  const int m0 = mt << 7, n0 = nt << 7;

  __shared__ __align__(16) unsigned char smem[32768];
  unsigned char* sA = smem;
  unsigned char* sB = smem + 16384;

  const f32x16 Z16 = {0.f, 0.f, 0.f, 0.f, 0.f, 0.f, 0.f, 0.f,
                      0.f, 0.f, 0.f, 0.f, 0.f, 0.f, 0.f, 0.f};
  f32x16 acc[2][2];
#pragma unroll
  for (int i = 0; i < 2; i++)
#pragma unroll
    for (int j = 0; j < 2; j++) acc[i][j] = Z16;

  const int chunkbase = w * 1024 + lane * 16;

  for (int kt = 0; kt < K; kt += 64) {
    // stage: linear LDS byte p -> (grow, gcol) via inverse paired-row swizzle
#pragma unroll
    for (int c = 0; c < 4; c++) {
      int p = c * 4096 + chunkbase;
      int lrow = p >> 8;                               // 256B LDS row (0..63)
      int inner = (p & 255) ^ ((lrow & 15) << 4);      // unswizzled inner
      int grow = lrow * 2 + (inner >> 7);              // tile row 0..127
      int gcol = (inner & 127) >> 1;                   // elem col 0..63
      GLOAD_LDS16(A + (size_t)(m0 + grow) * K + kt + gcol,
                  sA + c * 4096 + w * 1024);
      GLOAD_LDS16(B + (size_t)(n0 + grow) * K + kt + gcol,
                  sB + c * 4096 + w * 1024);
    }
    __syncthreads();
#pragma unroll
    for (int ks = 0; ks < 4; ks++) {  // K-steps of 16
      bf16x8 af[2], bfr[2];
      const int kbyte = ks * 32 + hb * 16;  // k elems = ks*16 + hb*8
#pragma unroll
      for (int i = 0; i < 2; i++) {
        int ar = wr * 64 + i * 32 + l31;
        int alr = ar >> 1;
        af[i] = *(const bf16x8*)(
            sA + alr * 256 + ((((ar & 1) << 7) | kbyte) ^ ((alr & 15) << 4)));
        int br = wc * 64 + i * 32 + l31;
        int blr = br >> 1;
        bfr[i] = *(const bf16x8*)(
            sB + blr * 256 + ((((br & 1) << 7) | kbyte) ^ ((blr & 15) << 4)));
      }
#pragma unroll
      for (int i = 0; i < 2; i++)
#pragma unroll
        for (int j = 0; j < 2; j++)
          acc[i][j] = __builtin_amdgcn_mfma_f32_32x32x16_bf16(
              af[i], bfr[j], acc[i][j], 0, 0, 0);
    }
    __syncthreads();
  }

  // epilogue: 32x32 C frag layout col=l31, row=(r&3)+8*(r>>2)+4*hb
#pragma unroll
  for (int mi = 0; mi < 2; mi++) {
#pragma unroll
    for (int nj = 0; nj < 2; nj++) {
      const int row0 = m0 + wr * 64 + mi * 32;
      const int col = n0 + wc * 64 + nj * 32 + l31;
      const float bv = bias[col];
      f32x16 v = acc[mi][nj];
#pragma unroll
      for (int r = 0; r < 16; r++) v[r] += bv;
      if (EPI == 0) {
        float* Cf = (float*)Cout;
#pragma unroll
        for (int r = 0; r < 16; r++) {
          int row = row0 + (r & 3) + 8 * (r >> 2) + 4 * hb;
          Cf[(size_t)row * N + col] = v[r];
        }
      } else {
        bf16* Cb = (bf16*)Cout;
        if (col < 4096) {  // q or k section (uniform per block)
#pragma unroll
          for (int r = 0; r < 16; r++) {
            int row = row0 + (r & 3) + 8 * (r >> 2) + 4 * hb;
            Cb[(size_t)row * 6144 + col] = (bf16)v[r];
          }
        } else {  // v section -> transposed vt[B,H,D,S], bf16x4 along s
          int dg = col - 4096;
          int hh = dg >> 7, dd = dg & 127;
#pragma unroll
          for (int q = 0; q < 4; q++) {
            int rowq = row0 + q * 8 + 4 * hb;  // rows rowq .. rowq+3
            int bb = rowq >> 11, ss = rowq & 2047;
            bf16x4 pk;
#pragma unroll
            for (int j2 = 0; j2 < 4; j2++) pk[j2] = (bf16)v[q * 4 + j2];
            *(bf16x4*)(vt + (size_t)((bb * 16 + hh) * 128 + dd) * 2048 + ss) =
                pk;
          }
        }
      }
    }
  }
}

// ---------------------------------------------------------------------------
// Kernel 3: flash attention, 8-warp 32x32 swapped-QK^T (proven R2 structure)
// + XCD-chunked block swizzle: flat grid 256; swz=(f&7)*32+(f>>3) gives each
// XCD 4 whole (b,h) panels (4MB K+VT, L2-resident) instead of 32 partial.
__global__ __launch_bounds__(512, 2) void attn_kernel(
    const bf16* __restrict__ qkv, const bf16* __restrict__ vt,
    const float* __restrict__ kbias, bf16* __restrict__ ctx) {
  const int tid = threadIdx.x;
  const int lane = tid & 63;
  const int w = tid >> 6;
  const int l31 = lane & 31;
  const int hb = lane >> 5;

  // XCD-chunked decode (256 blocks): qt fastest within a panel chunk.
  const int f = blockIdx.x;
  const int swzb = (f & 7) * 32 + (f >> 3);
  const int qt = swzb & 7;
  const int h = (swzb >> 3) & 15;
  const int b = swzb >> 7;

  __shared__ __align__(16) unsigned char smem[65536];  // 2 x (16K K + 16K VT)

  const int qrow0 = qt * 256 + w * 32;
  const size_t tokbase = (size_t)b * 2048;
  const size_t vtbase = (size_t)((b * 16 + h) * 128) * 2048;
  const float* biasb = kbias + b * 2048;
  const float Cmul = SM_SCALE * LOG2E;

  auto stage = [&](int t, int bufsel) {
    const int kv0 = t * 64;
    unsigned char* base = smem + bufsel * 32768;
#pragma unroll
    for (int c = 0; c < 2; c++) {
      int p = c * 8192 + tid * 16;
      int rowk = p >> 8, offk = p & 255;  // K: 64 rows x 256B
      int sbk = offk ^ ((rowk & 15) << 4);
      GLOAD_LDS16(qkv + (tokbase + kv0 + rowk) * 6144 + 2048 + h * 128 +
                      (sbk >> 1),
                  base + c * 8192 + w * 1024);
      int rowv = p >> 7, offv = p & 127;  // VT: 128 rows x 128B
      int sbv = offv ^ ((rowv & 7) << 4);
      GLOAD_LDS16(vt + vtbase + (size_t)rowv * 2048 + kv0 + (sbv >> 1),
                  base + 16384 + c * 8192 + w * 1024);
    }
  };

  stage(0, 0);

  // Q B-frags from global (lane: q=l31, d = ds*16 + hb*8 + j)
  bf16x8 qf[8];
#pragma unroll
  for (int ds = 0; ds < 8; ds++)
    qf[ds] = *(const bf16x8*)(qkv + (tokbase + qrow0 + l31) * 6144 + h * 128 +
                              ds * 16 + hb * 8);

  const f32x16 Z16 = {0.f, 0.f, 0.f, 0.f, 0.f, 0.f, 0.f, 0.f,
                      0.f, 0.f, 0.f, 0.f, 0.f, 0.f, 0.f, 0.f};
  f32x16 opv[4];  // O: row q=(r&3)+8*(r>>2)+4hb, col d=d0*32+l31
#pragma unroll
  for (int d0 = 0; d0 < 4; d0++) opv[d0] = Z16;
  float mrun = -15000.0f, lrun = 0.0f;

  __syncthreads();

  for (int t = 0; t < 32; t++) {
    const int buf = t & 1;
    const int kv0 = t * 64;
    if (t < 31) stage(t + 1, buf ^ 1);
    unsigned char* sK = smem + buf * 32768;
    unsigned char* sVT = sK + 16384;

    f32x4 bb[2][2][2];
#pragma unroll
    for (int kb = 0; kb < 2; kb++)
#pragma unroll
      for (int sb = 0; sb < 2; sb++)
#pragma unroll
        for (int g = 0; g < 2; g++)
          bb[kb][sb][g] = *(const f32x4*)(biasb + kv0 + kb * 32 + sb * 16 +
                                          g * 8 + 4 * hb);

    // ---- S^T = K Q^T : acc col = q = l31, row = key ----
    f32x16 accs[2];
    accs[0] = Z16; accs[1] = Z16;
    __builtin_amdgcn_s_setprio(1);
#pragma unroll
    for (int ds = 0; ds < 8; ds++) {
#pragma unroll
      for (int kb = 0; kb < 2; kb++) {
        int row = kb * 32 + l31;
        bf16x8 kf = *(const bf16x8*)(
            sK + row * 256 + ((ds * 32 + hb * 16) ^ ((row & 15) << 4)));
        accs[kb] = __builtin_amdgcn_mfma_f32_32x32x16_bf16(kf, qf[ds],
                                                           accs[kb], 0, 0, 0);
      }
    }
    __builtin_amdgcn_s_setprio(0);

    // ---- softmax in-register (lane owns q=l31, keys of its hb half) ----
#pragma unroll
    for (int kb = 0; kb < 2; kb++)
#pragma unroll
      for (int r = 0; r < 16; r++)
        accs[kb][r] =
            accs[kb][r] * Cmul + bb[kb][r >> 3][(r >> 2) & 1][r & 3];

    float vmax = accs[0][0];
#pragma unroll
    for (int kb = 0; kb < 2; kb++)
#pragma unroll
      for (int r = 0; r < 16; r++) vmax = fmaxf(vmax, accs[kb][r]);
    vmax = fmaxf(vmax, __shfl_xor(vmax, 32));

    if (__any(vmax > mrun + 8.0f)) {  // defer-max (T13)
      float mnew = fmaxf(mrun, vmax);
      float corr = EXP2(mrun - mnew);
      mrun = mnew;
      lrun *= corr;
#pragma unroll
      for (int r = 0; r < 16; r++) {
        float cv = __shfl(corr, (r & 3) + 8 * (r >> 2) + 4 * hb);
#pragma unroll
        for (int d0 = 0; d0 < 4; d0++) opv[d0][r] *= cv;
      }
    }

    float vsum = 0.0f;
#pragma unroll
    for (int kb = 0; kb < 2; kb++)
#pragma unroll
      for (int r = 0; r < 16; r++) {
        float p = EXP2(accs[kb][r] - mrun);
        accs[kb][r] = p;
        vsum += p;
      }
    vsum += __shfl_xor(vsum, 32);
    lrun += vsum;

    // ---- P -> bf16 A-frags via cvt_pk + permlane32_swap (T12) ----
    union { unsigned int w4[4]; bf16x8 v; } paf[4];
#pragma unroll
    for (int kb = 0; kb < 2; kb++)
#pragma unroll
      for (int sb = 0; sb < 2; sb++) {
        int r0 = sb * 8;
        unsigned int a0 = cvtpk_bf16(accs[kb][r0 + 0], accs[kb][r0 + 1]);
        unsigned int a1 = cvtpk_bf16(accs[kb][r0 + 2], accs[kb][r0 + 3]);
        unsigned int c0 = cvtpk_bf16(accs[kb][r0 + 4], accs[kb][r0 + 5]);
        unsigned int c1 = cvtpk_bf16(accs[kb][r0 + 6], accs[kb][r0 + 7]);
        plane32_swap(a0, c0);
        plane32_swap(a1, c1);
        int ks = kb * 2 + sb;
        paf[ks].w4[0] = a0; paf[ks].w4[1] = a1;
        paf[ks].w4[2] = c0; paf[ks].w4[3] = c1;
      }

    // ---- O += P V  (B-frag from VT: lane d=d0*32+l31, k=ks*16+hb*8+j) ----
    __builtin_amdgcn_s_setprio(1);
#pragma unroll
    for (int ks = 0; ks < 4; ks++) {
#pragma unroll
      for (int d0 = 0; d0 < 4; d0++) {
        int row = d0 * 32 + l31;
        bf16x8 vf = *(const bf16x8*)(
            sVT + row * 128 + ((ks * 32 + hb * 16) ^ ((row & 7) << 4)));
        opv[d0] = __builtin_amdgcn_mfma_f32_32x32x16_bf16(paf[ks].v, vf,
                                                          opv[d0], 0, 0, 0);
      }
    }
    __builtin_amdgcn_s_setprio(0);

    __syncthreads();  // drains stage(t+1) vmcnt + protects dbuf swap
  }

  // ---- epilogue: ctx = O / l ----
  float linv = 1.0f / lrun;
#pragma unroll
  for (int r = 0; r < 16; r++) {
    float lv = __shfl(linv, (r & 3) + 8 * (r >> 2) + 4 * hb);
    int row = qrow0 + (r & 3) + 8 * (r >> 2) + 4 * hb;
#pragma unroll
    for (int d0 = 0; d0 < 4; d0++)
      ctx[(tokbase + row) * 2048 + h * 128 + d0 * 32 + l31] =
          (bf16)(opv[d0][r] * lv);
  }
}

// ---------------------------------------------------------------------------
extern "C" void kernel_launch(void* const* d_in, const int* in_sizes, int n_in,
                              void* d_out, int out_size, void* d_ws,
                              size_t ws_size, hipStream_t stream) {
  const float* x     = (const float*)d_in[0];
  const float* W_in  = (const float*)d_in[1];
  const float* b_in  = (const float*)d_in[2];
  const float* W_out = (const float*)d_in[3];
  const float* b_out = (const float*)d_in[4];
  const unsigned char* mask = (const unsigned char*)d_in[5];
  (void)in_sizes; (void)n_in; (void)out_size; (void)ws_size;

  char* ws = (char*)d_ws;
  bf16* xb    = (bf16*)(ws + 0);           //  16.78 MB  x bf16 [4096,2048]
  bf16* wib   = (bf16*)(ws + 16777216);    //  25.17 MB  W_in bf16 [6144,2048]
  bf16* wob   = (bf16*)(ws + 41943040);    //   8.39 MB  W_out bf16 [2048,2048]
  bf16* qkv   = (bf16*)(ws + 50331648);    //  50.33 MB  qkv bf16 [4096,6144]
  bf16* vt    = (bf16*)(ws + 100663296);   //  16.78 MB  V^T bf16 [B,H,D,S]
  bf16* ctx   = (bf16*)(ws + 117440512);   //  16.78 MB  ctx bf16 [4096,2048]
  float* kbias = (float*)(ws + 134217728); //  16 KB     key bias f32 [B*S]

  pre_kernel<<<12289, 256, 0, stream>>>(x, W_in, W_out, mask, xb, wib, wob,
                                        kbias);
  gemm_nt<1><<<1536, 256, 0, stream>>>(xb, wib, b_in, (void*)qkv, vt, 4096,
                                       6144, 2048);
  attn_kernel<<<256, 512, 0, stream>>>(qkv, vt, kbias, ctx);
  gemm_nt<0><<<512, 256, 0, stream>>>(ctx, wob, b_out, d_out, (bf16*)nullptr,
                                      4096, 2048, 2048);
}

// Round 9
// 250.197 us; speedup vs baseline: 1.0826x; 1.0749x over previous
//
#include <hip/hip_runtime.h>
#include <hip/hip_bf16.h>

// ---------------------------------------------------------------------------
// MHA fused pipeline, bf16 MFMA path.  (R6 configuration — measured optimum)
//   pre_kernel: {x, W_in, W_out} f32 -> bf16 + mask -> key-bias (one launch)
//   qkv = x @ W_in^T + b_in   (128x128-tile gemm_nt, 16x16x32 MFMA, 897 TF)
//   flash attention: 8-warp 32x32 swapped-QK^T, in-register softmax,
//     XCD-chunked block swizzle (panels L2-resident per XCD)
//   out = ctx @ W_out^T + b_out  (gemm_nt, f32 output)
// B=2 S=2048 E=2048 H=16 D=128 hard-coded where convenient.
// Session ledger: R3-R5 pipelined GEMM ports 775-800 TF < 897 (rejected);
// R7 32x32 MFMA = 4-way LDS conflict (rejected); R8 conflict-free 32x32 =
// ILP-bound, 4 acc chains can't fill pipe at 2 waves/SIMD (rejected).
// ---------------------------------------------------------------------------

typedef __bf16 bf16;
typedef __bf16 bf16x8 __attribute__((ext_vector_type(8)));
typedef __bf16 bf16x4 __attribute__((ext_vector_type(4)));
typedef float  f32x4  __attribute__((ext_vector_type(4)));
typedef float  f32x16 __attribute__((ext_vector_type(16)));

#define LOG2E 1.4426950408889634074f
#define SM_SCALE 0.08838834764831843f /* 1/sqrt(128) */

#if defined(__has_builtin)
#if __has_builtin(__builtin_amdgcn_exp2f)
#define EXP2(x) __builtin_amdgcn_exp2f(x)
#else
#define EXP2(x) exp2f(x)
#endif
#else
#define EXP2(x) exp2f(x)
#endif

// global -> LDS direct copy, 16B per lane. LDS dest is wave-uniform base +
// lane*16 (hardware rule, m104); global src is per-lane.
#define GLOAD_LDS16(gp, lp)                                                    \
  __builtin_amdgcn_global_load_lds(                                           \
      (__attribute__((address_space(1))) void*)(gp),                          \
      (__attribute__((address_space(3))) void*)(lp), 16, 0, 0)

__device__ inline unsigned int cvtpk_bf16(float lo, float hi) {
  unsigned int r;
  asm("v_cvt_pk_bf16_f32 %0, %1, %2" : "=v"(r) : "v"(lo), "v"(hi));
  return r;
}
// v_permlane32_swap_b32: a.hi_lanes <-> b.lo_lanes
__device__ inline void plane32_swap(unsigned int& a, unsigned int& b) {
  asm volatile("v_permlane32_swap_b32 %0, %1" : "+v"(a), "+v"(b));
}

// ---------------------------------------------------------------------------
// Kernel 1: fused pre-pass. Blocks [0,12288): f32->bf16 convert (8 elem/thr);
// block 12288: mask -> additive key bias with storage-dtype sniffing.
// Ranges: [0,4096)->x, [4096,10240)->W_in, [10240,12288)->W_out. Exact fit.
__global__ void pre_kernel(const float* __restrict__ x,
                           const float* __restrict__ W_in,
                           const float* __restrict__ W_out,
                           const unsigned char* __restrict__ mraw,
                           bf16* __restrict__ xb, bf16* __restrict__ wib,
                           bf16* __restrict__ wob,
                           float* __restrict__ kbias) {
  const int bid = blockIdx.x;
  if (bid < 12288) {
    const float* in;
    bf16* out;
    int i;
    if (bid < 4096) {
      in = x; out = xb; i = bid * 256 + threadIdx.x;
    } else if (bid < 10240) {
      in = W_in; out = wib; i = (bid - 4096) * 256 + threadIdx.x;
    } else {
      in = W_out; out = wob; i = (bid - 10240) * 256 + threadIdx.x;
    }
    const float4* p = (const float4*)in + (size_t)i * 2;
    float4 a = p[0], c = p[1];
    bf16x8 v;
    v[0] = (bf16)a.x; v[1] = (bf16)a.y; v[2] = (bf16)a.z; v[3] = (bf16)a.w;
    v[4] = (bf16)c.x; v[5] = (bf16)c.y; v[6] = (bf16)c.z; v[7] = (bf16)c.w;
    *((bf16x8*)out + i) = v;
    return;
  }
  // ---- mask -> bias (block 12288) ----
  // dtype sniff from first 4096 bytes: nonzero @ (i%4==1) -> 1-byte bool;
  // else @ (i%4 in 2,3) -> f32; else @ (i%8==4) -> i32; else i64.
  __shared__ int f1, f23, f84;
  if (threadIdx.x == 0) { f1 = 0; f23 = 0; f84 = 0; }
  __syncthreads();
  int a1 = 0, a23 = 0, a84 = 0;
  for (int i = threadIdx.x; i < 4096; i += blockDim.x) {
    unsigned char v = mraw[i];
    if (v) {
      int m4 = i & 3;
      if (m4 == 1) a1 = 1;
      else if (m4 >= 2) a23 = 1;
      else if ((i & 7) == 4) a84 = 1;
    }
  }
  if (a1) f1 = 1;
  if (a23) f23 = 1;
  if (a84) f84 = 1;
  __syncthreads();
  const bool isByte = (f1 != 0);
  const bool isF32 = !isByte && (f23 != 0);
  const bool isI32 = !isByte && !isF32 && (f84 != 0);
  for (int i = threadIdx.x; i < 4096; i += blockDim.x) {
    int m;
    if (isByte)      m = (mraw[i] != 0);
    else if (isF32)  m = (((const float*)mraw)[i] != 0.0f);
    else if (isI32)  m = (((const int*)mraw)[i] != 0);
    else             m = (((const long long*)mraw)[i] != 0LL);
    kbias[i] = m ? -30000.0f : 0.0f;  // exp2-domain "-inf"
  }
}

// ---------------------------------------------------------------------------
// Kernel 2: NT GEMM  C[M,N] = A[M,K] * B[N,K]^T + bias[N]  (proven m97
// structure: 128x128 tile, BK=64, 4 waves 2x2, global_load_lds w16, XOR
// swizzle on source+ds_read, 2 blocks/CU, 16x16x32 MFMA = 16 indep chains).
// EPI=0: f32 store. EPI=1: qkv routing (cols<4096 -> qkv; else vt transposed).
template <int EPI>
__global__ __launch_bounds__(256, 2) void gemm_nt(
    const bf16* __restrict__ A, const bf16* __restrict__ B,
    const float* __restrict__ bias, void* __restrict__ Cout,
    bf16* __restrict__ vt, int M, int N, int K) {
  const int lane = threadIdx.x & 63;
  const int w = threadIdx.x >> 6;
  const int wr = w >> 1, wc = w & 1;
  const int l15 = lane & 15, lg = lane >> 4;

  const int nwg = gridDim.x;  // multiple of 8 for all launches
  const int cpx = nwg >> 3;
  const int bid = blockIdx.x;
  const int swz = (bid & 7) * cpx + (bid >> 3);
  const int mtiles = M >> 7;
  const int mt = swz % mtiles, nt = swz / mtiles;
  const int m0 = mt << 7, n0 = nt << 7;

  __shared__ __align__(16) unsigned char smem[32768];
  unsigned char* sA = smem;
  unsigned char* sB = smem + 16384;

  const f32x4 Z4 = {0.f, 0.f, 0.f, 0.f};
  f32x4 acc[4][4];
#pragma unroll
  for (int i = 0; i < 4; i++)
#pragma unroll
    for (int j = 0; j < 4; j++) acc[i][j] = Z4;

  const int chunkbase = w * 1024 + lane * 16;

  for (int kt = 0; kt < K; kt += 64) {
#pragma unroll
    for (int c = 0; c < 4; c++) {
      int p = c * 4096 + chunkbase;
      int row = p >> 7, off = p & 127;
      int sb = off ^ ((row & 7) << 4);
      GLOAD_LDS16(A + (size_t)(m0 + row) * K + kt + (sb >> 1),
                  sA + c * 4096 + w * 1024);
      GLOAD_LDS16(B + (size_t)(n0 + row) * K + kt + (sb >> 1),
                  sB + c * 4096 + w * 1024);
    }
    __syncthreads();
#pragma unroll
    for (int ks = 0; ks < 2; ks++) {
      bf16x8 af[4], bfr[4];
#pragma unroll
      for (int i = 0; i < 4; i++) {
        int ar = wr * 64 + i * 16 + l15;
        af[i] = *(const bf16x8*)(sA + ar * 128 +
                                 ((ks * 64 + lg * 16) ^ ((ar & 7) << 4)));
        int br = wc * 64 + i * 16 + l15;
        bfr[i] = *(const bf16x8*)(sB + br * 128 +
                                  ((ks * 64 + lg * 16) ^ ((br & 7) << 4)));
      }
#pragma unroll
      for (int i = 0; i < 4; i++)
#pragma unroll
        for (int j = 0; j < 4; j++)
          acc[i][j] = __builtin_amdgcn_mfma_f32_16x16x32_bf16(
              af[i], bfr[j], acc[i][j], 0, 0, 0);
    }
    __syncthreads();
  }

  // epilogue: C frag layout col=lane&15, row=(lane>>4)*4+r (m89-verified)
#pragma unroll
  for (int i = 0; i < 4; i++) {
#pragma unroll
    for (int j = 0; j < 4; j++) {
      const int row0 = m0 + wr * 64 + i * 16 + lg * 4;
      const int col = n0 + wc * 64 + j * 16 + l15;
      const float bv = bias[col];
      f32x4 v = acc[i][j];
#pragma unroll
      for (int r = 0; r < 4; r++) v[r] += bv;
      if (EPI == 0) {
        float* Cf = (float*)Cout;
#pragma unroll
        for (int r = 0; r < 4; r++)
          Cf[(size_t)(row0 + r) * N + col] = v[r];
      } else {
        bf16* Cb = (bf16*)Cout;
        if (col < 4096) {  // q or k section (uniform per block)
#pragma unroll
          for (int r = 0; r < 4; r++)
            Cb[(size_t)(row0 + r) * 6144 + col] = (bf16)v[r];
        } else {  // v section -> transposed vt[B,H,D,S]
          int dg = col - 4096;
          int hh = dg >> 7, dd = dg & 127;
          int bb = row0 >> 11, ss = row0 & 2047;
          bf16x4 pk;
#pragma unroll
          for (int r = 0; r < 4; r++) pk[r] = (bf16)v[r];
          *(bf16x4*)(vt + (size_t)((bb * 16 + hh) * 128 + dd) * 2048 + ss) = pk;
        }
      }
    }
  }
}

// ---------------------------------------------------------------------------
// Kernel 3: flash attention, 8-warp 32x32 swapped-QK^T (proven R2 structure)
// + XCD-chunked block swizzle: flat grid 256; swz=(f&7)*32+(f>>3) gives each
// XCD 4 whole (b,h) panels (4MB K+VT, L2-resident) instead of 32 partial.
__global__ __launch_bounds__(512, 2) void attn_kernel(
    const bf16* __restrict__ qkv, const bf16* __restrict__ vt,
    const float* __restrict__ kbias, bf16* __restrict__ ctx) {
  const int tid = threadIdx.x;
  const int lane = tid & 63;
  const int w = tid >> 6;
  const int l31 = lane & 31;
  const int hb = lane >> 5;

  // XCD-chunked decode (256 blocks): qt fastest within a panel chunk.
  const int f = blockIdx.x;
  const int swzb = (f & 7) * 32 + (f >> 3);
  const int qt = swzb & 7;
  const int h = (swzb >> 3) & 15;
  const int b = swzb >> 7;

  __shared__ __align__(16) unsigned char smem[65536];  // 2 x (16K K + 16K VT)

  const int qrow0 = qt * 256 + w * 32;
  const size_t tokbase = (size_t)b * 2048;
  const size_t vtbase = (size_t)((b * 16 + h) * 128) * 2048;
  const float* biasb = kbias + b * 2048;
  const float Cmul = SM_SCALE * LOG2E;

  auto stage = [&](int t, int bufsel) {
    const int kv0 = t * 64;
    unsigned char* base = smem + bufsel * 32768;
#pragma unroll
    for (int c = 0; c < 2; c++) {
      int p = c * 8192 + tid * 16;
      int rowk = p >> 8, offk = p & 255;  // K: 64 rows x 256B
      int sbk = offk ^ ((rowk & 15) << 4);
      GLOAD_LDS16(qkv + (tokbase + kv0 + rowk) * 6144 + 2048 + h * 128 +
                      (sbk >> 1),
                  base + c * 8192 + w * 1024);
      int rowv = p >> 7, offv = p & 127;  // VT: 128 rows x 128B
      int sbv = offv ^ ((rowv & 7) << 4);
      GLOAD_LDS16(vt + vtbase + (size_t)rowv * 2048 + kv0 + (sbv >> 1),
                  base + 16384 + c * 8192 + w * 1024);
    }
  };

  stage(0, 0);

  // Q B-frags from global (lane: q=l31, d = ds*16 + hb*8 + j)
  bf16x8 qf[8];
#pragma unroll
  for (int ds = 0; ds < 8; ds++)
    qf[ds] = *(const bf16x8*)(qkv + (tokbase + qrow0 + l31) * 6144 + h * 128 +
                              ds * 16 + hb * 8);

  const f32x16 Z16 = {0.f, 0.f, 0.f, 0.f, 0.f, 0.f, 0.f, 0.f,
                      0.f, 0.f, 0.f, 0.f, 0.f, 0.f, 0.f, 0.f};
  f32x16 opv[4];  // O: row q=(r&3)+8*(r>>2)+4hb, col d=d0*32+l31
#pragma unroll
  for (int d0 = 0; d0 < 4; d0++) opv[d0] = Z16;
  float mrun = -15000.0f, lrun = 0.0f;

  __syncthreads();

  for (int t = 0; t < 32; t++) {
    const int buf = t & 1;
    const int kv0 = t * 64;
    if (t < 31) stage(t + 1, buf ^ 1);
    unsigned char* sK = smem + buf * 32768;
    unsigned char* sVT = sK + 16384;

    f32x4 bb[2][2][2];
#pragma unroll
    for (int kb = 0; kb < 2; kb++)
#pragma unroll
      for (int sb = 0; sb < 2; sb++)
#pragma unroll
        for (int g = 0; g < 2; g++)
          bb[kb][sb][g] = *(const f32x4*)(biasb + kv0 + kb * 32 + sb * 16 +
                                          g * 8 + 4 * hb);

    // ---- S^T = K Q^T : acc col = q = l31, row = key ----
    f32x16 accs[2];
    accs[0] = Z16; accs[1] = Z16;
    __builtin_amdgcn_s_setprio(1);
#pragma unroll
    for (int ds = 0; ds < 8; ds++) {
#pragma unroll
      for (int kb = 0; kb < 2; kb++) {
        int row = kb * 32 + l31;
        bf16x8 kf = *(const bf16x8*)(
            sK + row * 256 + ((ds * 32 + hb * 16) ^ ((row & 15) << 4)));
        accs[kb] = __builtin_amdgcn_mfma_f32_32x32x16_bf16(kf, qf[ds],
                                                           accs[kb], 0, 0, 0);
      }
    }
    __builtin_amdgcn_s_setprio(0);

    // ---- softmax in-register (lane owns q=l31, keys of its hb half) ----
#pragma unroll
    for (int kb = 0; kb < 2; kb++)
#pragma unroll
      for (int r = 0; r < 16; r++)
        accs[kb][r] =
            accs[kb][r] * Cmul + bb[kb][r >> 3][(r >> 2) & 1][r & 3];

    float vmax = accs[0][0];
#pragma unroll
    for (int kb = 0; kb < 2; kb++)
#pragma unroll
      for (int r = 0; r < 16; r++) vmax = fmaxf(vmax, accs[kb][r]);
    vmax = fmaxf(vmax, __shfl_xor(vmax, 32));

    if (__any(vmax > mrun + 8.0f)) {  // defer-max (T13)
      float mnew = fmaxf(mrun, vmax);
      float corr = EXP2(mrun - mnew);
      mrun = mnew;
      lrun *= corr;
#pragma unroll
      for (int r = 0; r < 16; r++) {
        float cv = __shfl(corr, (r & 3) + 8 * (r >> 2) + 4 * hb);
#pragma unroll
        for (int d0 = 0; d0 < 4; d0++) opv[d0][r] *= cv;
      }
    }

    float vsum = 0.0f;
#pragma unroll
    for (int kb = 0; kb < 2; kb++)
#pragma unroll
      for (int r = 0; r < 16; r++) {
        float p = EXP2(accs[kb][r] - mrun);
        accs[kb][r] = p;
        vsum += p;
      }
    vsum += __shfl_xor(vsum, 32);
    lrun += vsum;

    // ---- P -> bf16 A-frags via cvt_pk + permlane32_swap (T12) ----
    union { unsigned int w4[4]; bf16x8 v; } paf[4];
#pragma unroll
    for (int kb = 0; kb < 2; kb++)
#pragma unroll
      for (int sb = 0; sb < 2; sb++) {
        int r0 = sb * 8;
        unsigned int a0 = cvtpk_bf16(accs[kb][r0 + 0], accs[kb][r0 + 1]);
        unsigned int a1 = cvtpk_bf16(accs[kb][r0 + 2], accs[kb][r0 + 3]);
        unsigned int c0 = cvtpk_bf16(accs[kb][r0 + 4], accs[kb][r0 + 5]);
        unsigned int c1 = cvtpk_bf16(accs[kb][r0 + 6], accs[kb][r0 + 7]);
        plane32_swap(a0, c0);
        plane32_swap(a1, c1);
        int ks = kb * 2 + sb;
        paf[ks].w4[0] = a0; paf[ks].w4[1] = a1;
        paf[ks].w4[2] = c0; paf[ks].w4[3] = c1;
      }

    // ---- O += P V  (B-frag from VT: lane d=d0*32+l31, k=ks*16+hb*8+j) ----
    __builtin_amdgcn_s_setprio(1);
#pragma unroll
    for (int ks = 0; ks < 4; ks++) {
#pragma unroll
      for (int d0 = 0; d0 < 4; d0++) {
        int row = d0 * 32 + l31;
        bf16x8 vf = *(const bf16x8*)(
            sVT + row * 128 + ((ks * 32 + hb * 16) ^ ((row & 7) << 4)));
        opv[d0] = __builtin_amdgcn_mfma_f32_32x32x16_bf16(paf[ks].v, vf,
                                                          opv[d0], 0, 0, 0);
      }
    }
    __builtin_amdgcn_s_setprio(0);

    __syncthreads();  // drains stage(t+1) vmcnt + protects dbuf swap
  }

  // ---- epilogue: ctx = O / l ----
  float linv = 1.0f / lrun;
#pragma unroll
  for (int r = 0; r < 16; r++) {
    float lv = __shfl(linv, (r & 3) + 8 * (r >> 2) + 4 * hb);
    int row = qrow0 + (r & 3) + 8 * (r >> 2) + 4 * hb;
#pragma unroll
    for (int d0 = 0; d0 < 4; d0++)
      ctx[(tokbase + row) * 2048 + h * 128 + d0 * 32 + l31] =
          (bf16)(opv[d0][r] * lv);
  }
}

// ---------------------------------------------------------------------------
extern "C" void kernel_launch(void* const* d_in, const int* in_sizes, int n_in,
                              void* d_out, int out_size, void* d_ws,
                              size_t ws_size, hipStream_t stream) {
  const float* x     = (const float*)d_in[0];
  const float* W_in  = (const float*)d_in[1];
  const float* b_in  = (const float*)d_in[2];
  const float* W_out = (const float*)d_in[3];
  const float* b_out = (const float*)d_in[4];
  const unsigned char* mask = (const unsigned char*)d_in[5];
  (void)in_sizes; (void)n_in; (void)out_size; (void)ws_size;

  char* ws = (char*)d_ws;
  bf16* xb    = (bf16*)(ws + 0);           //  16.78 MB  x bf16 [4096,2048]
  bf16* wib   = (bf16*)(ws + 16777216);    //  25.17 MB  W_in bf16 [6144,2048]
  bf16* wob   = (bf16*)(ws + 41943040);    //   8.39 MB  W_out bf16 [2048,2048]
  bf16* qkv   = (bf16*)(ws + 50331648);    //  50.33 MB  qkv bf16 [4096,6144]
  bf16* vt    = (bf16*)(ws + 100663296);   //  16.78 MB  V^T bf16 [B,H,D,S]
  bf16* ctx   = (bf16*)(ws + 117440512);   //  16.78 MB  ctx bf16 [4096,2048]
  float* kbias = (float*)(ws + 134217728); //  16 KB     key bias f32 [B*S]

  pre_kernel<<<12289, 256, 0, stream>>>(x, W_in, W_out, mask, xb, wib, wob,
                                        kbias);
  gemm_nt<1><<<1536, 256, 0, stream>>>(xb, wib, b_in, (void*)qkv, vt, 4096,
                                       6144, 2048);
  attn_kernel<<<256, 512, 0, stream>>>(qkv, vt, kbias, ctx);
  gemm_nt<0><<<512, 256, 0, stream>>>(ctx, wob, b_out, d_out, (bf16*)nullptr,
                                      4096, 2048, 2048);
}